// Round 6
// baseline (63.284 us; speedup 1.0000x reference)
//
#include <hip/hip_runtime.h>
#include <hip/hip_bf16.h>

// ChamferDistanceLoss via exact-integer f16 MFMA (16x16x32), refs-as-A-rows:
//   A (rows, L2-streamed)   = refs    enc [rd, rh, rw, nr>>3, nr&7, 0,0,0]  (k=0..7)
//   B (cols, register-held) = queries enc [-2qd, -2qh, -2qw, 8, 1, 0,0,0]
// Lanes 16-63 supply A k=8..31 from a guaranteed-zero slot -> B garbage there
// is nullified; no lane masking anywhere in the hot loop.
// s = nr - 2 q.r exact (f16 operands exact small ints, fp32 products exact).
// D frag: col=lane&15 (query), row=(lane>>4)*4+e (ref). Per MFMA: 2 v_min3.
// min commutes with +nq; scale by (2/63)^2 at the end.

#define NVOX      262144
#define NCHUNK    256
#define MAXPTS    10000
#define PTS_PAD   10240
#define NCLOUD    8
#define NTASK     8
#define NRB       40         // reduce blocks per task
#define QPW       128        // queries per wave (8 B-frags x 16)
#define QPB       512        // queries per block (4 waves)
#define NQB       20         // query blocks per task
#define RSPLIT    8          // ref splits per task
#define RLEN      1280       // refs per split
#define RSTEPS    80         // 16-ref steps per split
#define SCALE     (2.0f/63.0f)

typedef _Float16 half8 __attribute__((ext_vector_type(8)));
typedef float    f32x4 __attribute__((ext_vector_type(4)));

// ---------------- workspace layout (bytes) ----------------
#define WS_TOTALS   0           // 8 ints
#define WS_COUNTS   1024        // 8*256 ints
#define WS_OFFSETS  16384       // 8*256 ints
#define WS_QFRAG    32768       // 8*10240*16B = 1310720
#define WS_RFRAG    1343488     // 8*10240*16B = 1310720
#define WS_NQ       2654208     // 8*10240 f32 = 327680
#define WS_SMIN     2981888     // 8*8*10240 f32 = 2621440
#define WS_BSUM     5603328     // 8*40 f32

__device__ __forceinline__ const float* cloud_src(const float* pred, const float* tgt, int cloud) {
    const float* base = (cloud & 1) ? tgt : pred;
    return base + (size_t)(cloud >> 1) * NVOX;
}

// ---- Kernel 1: per-chunk active counts (+ pad init, merged) ----------------
__global__ void k_count(const float* __restrict__ pred, const float* __restrict__ tgt,
                        int* __restrict__ counts,
                        half8* __restrict__ Qfrag, half8* __restrict__ Rfrag,
                        float* __restrict__ nqint) {
    int gi = blockIdx.x * 256 + threadIdx.x;
    if (gi < NCLOUD * PTS_PAD) {   // init pads; compact overwrites ranks < MAXPTS only,
        half8 zq = {0, 0, 0, 0, 0, 0, 0, 0};   // so Qfrag[...][10000..10239] stays ZERO
        half8 zr = {0, 0, 0, (_Float16)4096, 0, 0, 0, 0};   // pad ref: s=8*4096=32768 > any real
        Qfrag[gi] = zq;
        Rfrag[gi] = zr;
        nqint[gi] = 0.f;
    }
    int cloud = blockIdx.x >> 8;
    int chunk = blockIdx.x & 255;
    int t = threadIdx.x;
    const float* src = cloud_src(pred, tgt, cloud) + chunk * 1024;
    float4 v = reinterpret_cast<const float4*>(src)[t];
    int cnt = (v.x > 0.5f) + (v.y > 0.5f) + (v.z > 0.5f) + (v.w > 0.5f);
    __shared__ int s[256];
    s[t] = cnt; __syncthreads();
    for (int o = 128; o > 0; o >>= 1) {
        if (t < o) s[t] += s[t + o];
        __syncthreads();
    }
    if (t == 0) counts[cloud * NCHUNK + chunk] = s[0];
}

// ---- Kernel 2: exclusive scan of chunk counts per cloud --------------------
__global__ void k_scan(const int* __restrict__ counts, int* __restrict__ offsets,
                       int* __restrict__ totals) {
    int cloud = blockIdx.x;
    int t = threadIdx.x;
    int c = counts[cloud * NCHUNK + t];
    __shared__ int s[256];
    s[t] = c; __syncthreads();
    for (int o = 1; o < 256; o <<= 1) {
        int v = (t >= o) ? s[t - o] : 0;
        __syncthreads();
        s[t] += v;
        __syncthreads();
    }
    offsets[cloud * NCHUNK + t] = s[t] - c;
    if (t == 255) totals[cloud] = s[255];
}

// ---- Kernel 3: ordered compaction -> Q/R fragments + nq --------------------
__global__ void k_compact(const float* __restrict__ pred, const float* __restrict__ tgt,
                          const int* __restrict__ offsets,
                          half8* __restrict__ Qfrag, half8* __restrict__ Rfrag,
                          float* __restrict__ nqint) {
    int cloud = blockIdx.x >> 8;
    int chunk = blockIdx.x & 255;
    int t = threadIdx.x;
    const float* src = cloud_src(pred, tgt, cloud) + chunk * 1024;
    float4 v = reinterpret_cast<const float4*>(src)[t];
    int f0 = v.x > 0.5f, f1 = v.y > 0.5f, f2 = v.z > 0.5f, f3 = v.w > 0.5f;
    int cnt = f0 + f1 + f2 + f3;
    __shared__ int s[256];
    s[t] = cnt; __syncthreads();
    for (int o = 1; o < 256; o <<= 1) {
        int x = (t >= o) ? s[t - o] : 0;
        __syncthreads();
        s[t] += x;
        __syncthreads();
    }
    int rank = offsets[cloud * NCHUNK + chunk] + (s[t] - cnt);
    int eidx = chunk * 1024 + t * 4;
    int flags[4] = {f0, f1, f2, f3};
    size_t base = (size_t)cloud * PTS_PAD;
    #pragma unroll
    for (int e = 0; e < 4; ++e) {
        if (flags[e]) {
            if (rank < MAXPTS) {
                int idx = eidx + e;
                int d = idx >> 12, h = (idx >> 6) & 63, w = idx & 63;
                int nr = d * d + h * h + w * w;
                half8 Q = {(_Float16)(-2 * d), (_Float16)(-2 * h), (_Float16)(-2 * w),
                           (_Float16)8, (_Float16)1, 0, 0, 0};
                half8 R = {(_Float16)d, (_Float16)h, (_Float16)w,
                           (_Float16)(nr >> 3), (_Float16)(nr & 7), 0, 0, 0};
                Qfrag[base + rank] = Q;
                Rfrag[base + rank] = R;
                nqint[base + rank] = (float)nr;
            }
            rank++;
        }
    }
}

// ---- Kernel 4: chamfer min via 16x16x32 MFMA, refs streamed from L2 --------
// grid = NTASK*NQB*RSPLIT = 1280 blocks, 256 thr (4 waves), no LDS.
// Wave holds 128 queries (8 B-frags); per step loads 16 refs (one 256B region,
// L2-resident) as the A-frag and issues 8 MFMA + 16 v_min3.
__global__ __launch_bounds__(256, 4) void k_chamfer(const half8* __restrict__ Qfrag,
                                                    const half8* __restrict__ Rfrag,
                                                    float* __restrict__ smin) {
    int task = blockIdx.x / (NQB * RSPLIT);
    int rem  = blockIdx.x % (NQB * RSPLIT);
    int qb   = rem / RSPLIT;
    int rs   = rem % RSPLIT;
    int b = task >> 1, dir = task & 1;
    int qc = 2 * b + dir;
    int rc = 2 * b + (dir ^ 1);
    int tid = threadIdx.x, wave = tid >> 6, lane = tid & 63;
    int l16 = lane & 15;

    int qbase = qb * QPB + wave * QPW;
    const half8* qp = Qfrag + (size_t)qc * PTS_PAD + qbase + l16;
    half8 bq[8];
    #pragma unroll
    for (int f = 0; f < 8; ++f) bq[f] = qp[f * 16];   // all lanes: garbage x A-zero ok

    float m[8];
    #pragma unroll
    for (int f = 0; f < 8; ++f) m[f] = 1e30f;
    f32x4 cz4 = {0.f, 0.f, 0.f, 0.f};

    // A source: lanes 0-15 stream refs; lanes 16-63 re-read a guaranteed-zero
    // 16B slot (Qfrag tail, never written) so A[k>=8]=0.
    const char* rbase;
    int rstep;
    if (lane < 16) {
        rbase = (const char*)(Rfrag + (size_t)rc * PTS_PAD + rs * RLEN + l16);
        rstep = 16 * 16;
    } else {
        rbase = (const char*)(Qfrag + MAXPTS + 100);   // zero half8
        rstep = 0;
    }

    #pragma unroll 4
    for (int t = 0; t < RSTEPS; ++t) {
        half8 a = *(const half8*)rbase;
        rbase += rstep;
        #pragma unroll
        for (int f = 0; f < 8; ++f) {
            f32x4 d_ = __builtin_amdgcn_mfma_f32_16x16x32_f16(a, bq[f], cz4, 0, 0, 0);
            asm("" : "+v"(d_));
            float t_ = fminf(fminf(d_[0], d_[1]), d_[2]);   // v_min3
            m[f] = fminf(fminf(m[f], t_), d_[3]);           // v_min3
        }
    }

    // lane holds ref-rows {(lane>>4)*4..+3} for query col l16: combine groups
    #pragma unroll
    for (int f = 0; f < 8; ++f) {
        m[f] = fminf(m[f], __shfl_xor(m[f], 16));
        m[f] = fminf(m[f], __shfl_xor(m[f], 32));
    }
    if (lane < 16) {
        float* outp = smin + ((size_t)task * RSPLIT + rs) * PTS_PAD + qbase + l16;
        #pragma unroll
        for (int f = 0; f < 8; ++f) outp[f * 16] = m[f];
    }
}

// ---- Kernel 5: min over splits, add nq, scale, clamp, masked block sum -----
__global__ void k_reduce(const float* __restrict__ nqint, const int* __restrict__ totals,
                         const float* __restrict__ smin, float* __restrict__ bsum) {
    int task = blockIdx.x / NRB;
    int rb   = blockIdx.x % NRB;
    int tid  = threadIdx.x;
    int qi   = rb * 256 + tid;
    int qc   = 2 * (task >> 1) + (task & 1);
    int countQ = min(totals[qc], MAXPTS);

    const float SC2 = SCALE * SCALE;
    float contrib = 0.f;
    if (qi < countQ) {
        const float* s = smin + (size_t)task * RSPLIT * PTS_PAD + qi;
        float mn = fminf(fminf(s[0 * PTS_PAD], s[1 * PTS_PAD]),
                         fminf(s[2 * PTS_PAD], s[3 * PTS_PAD]));
        mn = fminf(mn, fminf(fminf(s[4 * PTS_PAD], s[5 * PTS_PAD]),
                             fminf(s[6 * PTS_PAD], s[7 * PTS_PAD])));
        float nq = nqint[(size_t)qc * PTS_PAD + qi];
        contrib = fmaxf((nq + mn) * SC2, 0.f);
    }
    __shared__ float sb[256];
    sb[tid] = contrib; __syncthreads();
    for (int o = 128; o > 0; o >>= 1) {
        if (tid < o) sb[tid] += sb[tid + o];
        __syncthreads();
    }
    if (tid == 0) bsum[task * NRB + rb] = sb[0];
}

// ---- Kernel 6: deterministic final combine ---------------------------------
__global__ void k_final(const float* __restrict__ bsum, const int* __restrict__ totals,
                        float* __restrict__ out) {
    float total = 0.f, nv = 0.f;
    for (int b = 0; b < 4; ++b) {
        float s1 = 0.f, s2 = 0.f;
        for (int i = 0; i < NRB; ++i) {
            s1 += bsum[(2 * b) * NRB + i];
            s2 += bsum[(2 * b + 1) * NRB + i];
        }
        int c1 = min(totals[2 * b], MAXPTS);
        int c2 = min(totals[2 * b + 1], MAXPTS);
        float cd = s1 / fmaxf((float)c1, 1.f) + s2 / fmaxf((float)c2, 1.f);
        if (c1 > 0 && c2 > 0) { total += cd; nv += 1.f; }
    }
    out[0] = (nv > 0.f) ? total / nv : 0.f;
}

extern "C" void kernel_launch(void* const* d_in, const int* in_sizes, int n_in,
                              void* d_out, int out_size, void* d_ws, size_t ws_size,
                              hipStream_t stream) {
    const float* pred = (const float*)d_in[0];
    const float* tgt  = (const float*)d_in[1];
    float* out = (float*)d_out;

    char* ws = (char*)d_ws;
    int*   totals  = (int*)(ws + WS_TOTALS);
    int*   counts  = (int*)(ws + WS_COUNTS);
    int*   offsets = (int*)(ws + WS_OFFSETS);
    half8* Qfrag   = (half8*)(ws + WS_QFRAG);
    half8* Rfrag   = (half8*)(ws + WS_RFRAG);
    float* nqint   = (float*)(ws + WS_NQ);
    float* smin    = (float*)(ws + WS_SMIN);
    float* bsum    = (float*)(ws + WS_BSUM);

    k_count  <<<NCLOUD * NCHUNK, 256, 0, stream>>>(pred, tgt, counts, Qfrag, Rfrag, nqint);
    k_scan   <<<NCLOUD,          256, 0, stream>>>(counts, offsets, totals);
    k_compact<<<NCLOUD * NCHUNK, 256, 0, stream>>>(pred, tgt, offsets, Qfrag, Rfrag, nqint);
    k_chamfer<<<NTASK * NQB * RSPLIT, 256, 0, stream>>>(Qfrag, Rfrag, smin);
    k_reduce <<<NTASK * NRB,     256, 0, stream>>>(nqint, totals, smin, bsum);
    k_final  <<<1, 1, 0, stream>>>(bsum, totals, out);
}

// Round 7
// 60.591 us; speedup vs baseline: 1.0445x; 1.0445x over previous
//
#include <hip/hip_runtime.h>
#include <hip/hip_bf16.h>

// ChamferDistanceLoss via exact-integer f16 MFMA (32x32x16), inline-asm MFMA
// with "=v" dests (forces VGPR-class accumulators; no accvgpr copies).
//   A (rows, L2-streamed)   = refs    enc [rd, rh, rw, nr>>3, nr&7, 0,0,0]
//   B (cols, register-held) = queries enc [-2qd, -2qh, -2qw, 8, 1, 0,0,0]
// B zeroed on lanes>=32 (k=8..15) -> A garbage there nullified.
// s = nr - 2 q.r exact (f16 operands exact small ints, fp32 products exact).
// Hazard: 3x s_nop 7 after MFMA cluster before VALU reads the dests.
// min commutes with +nq; scale by (2/63)^2 at the end.

#define NVOX      262144
#define NCHUNK    256
#define MAXPTS    10000
#define PTS_PAD   10240
#define NCLOUD    8
#define NTASK     8
#define NRB       40         // reduce blocks per task
#define QPW       160        // queries per wave (5 B-frags x 32)
#define QPB       640        // queries per block (4 waves)
#define NQB       16         // query blocks per task
#define RSPLIT    8          // ref splits per task
#define RLEN      1280       // refs per split
#define RSTEPS    40         // 32-ref steps per split
#define SCALE     (2.0f/63.0f)

typedef _Float16 half8  __attribute__((ext_vector_type(8)));
typedef float    f32x16 __attribute__((ext_vector_type(16)));

// ---------------- workspace layout (bytes) ----------------
#define WS_TOTALS   0           // 8 ints
#define WS_COUNTS   1024        // 8*256 ints
#define WS_OFFSETS  16384       // 8*256 ints
#define WS_QFRAG    32768       // 8*10240*16B = 1310720
#define WS_RFRAG    1343488     // 8*10240*16B = 1310720
#define WS_NQ       2654208     // 8*10240 f32 = 327680
#define WS_SMIN     2981888     // 8*8*10240 f32 = 2621440
#define WS_BSUM     5603328     // 8*40 f32

__device__ __forceinline__ const float* cloud_src(const float* pred, const float* tgt, int cloud) {
    const float* base = (cloud & 1) ? tgt : pred;
    return base + (size_t)(cloud >> 1) * NVOX;
}

// ---- Kernel 1: per-chunk active counts (+ pad init, merged) ----------------
__global__ void k_count(const float* __restrict__ pred, const float* __restrict__ tgt,
                        int* __restrict__ counts,
                        half8* __restrict__ Qfrag, half8* __restrict__ Rfrag,
                        float* __restrict__ nqint) {
    int gi = blockIdx.x * 256 + threadIdx.x;
    if (gi < NCLOUD * PTS_PAD) {   // init pads; compact overwrites ranks < total only
        half8 zq = {0, 0, 0, 0, 0, 0, 0, 0};
        half8 zr = {0, 0, 0, (_Float16)4096, 0, 0, 0, 0};   // pad ref: s=8*4096=32768 > any real
        Qfrag[gi] = zq;
        Rfrag[gi] = zr;
        nqint[gi] = 0.f;
    }
    int cloud = blockIdx.x >> 8;
    int chunk = blockIdx.x & 255;
    int t = threadIdx.x;
    const float* src = cloud_src(pred, tgt, cloud) + chunk * 1024;
    float4 v = reinterpret_cast<const float4*>(src)[t];
    int cnt = (v.x > 0.5f) + (v.y > 0.5f) + (v.z > 0.5f) + (v.w > 0.5f);
    __shared__ int s[256];
    s[t] = cnt; __syncthreads();
    for (int o = 128; o > 0; o >>= 1) {
        if (t < o) s[t] += s[t + o];
        __syncthreads();
    }
    if (t == 0) counts[cloud * NCHUNK + chunk] = s[0];
}

// ---- Kernel 2: exclusive scan of chunk counts per cloud --------------------
__global__ void k_scan(const int* __restrict__ counts, int* __restrict__ offsets,
                       int* __restrict__ totals) {
    int cloud = blockIdx.x;
    int t = threadIdx.x;
    int c = counts[cloud * NCHUNK + t];
    __shared__ int s[256];
    s[t] = c; __syncthreads();
    for (int o = 1; o < 256; o <<= 1) {
        int v = (t >= o) ? s[t - o] : 0;
        __syncthreads();
        s[t] += v;
        __syncthreads();
    }
    offsets[cloud * NCHUNK + t] = s[t] - c;
    if (t == 255) totals[cloud] = s[255];
}

// ---- Kernel 3: ordered compaction -> Q/R fragments + nq --------------------
__global__ void k_compact(const float* __restrict__ pred, const float* __restrict__ tgt,
                          const int* __restrict__ offsets,
                          half8* __restrict__ Qfrag, half8* __restrict__ Rfrag,
                          float* __restrict__ nqint) {
    int cloud = blockIdx.x >> 8;
    int chunk = blockIdx.x & 255;
    int t = threadIdx.x;
    const float* src = cloud_src(pred, tgt, cloud) + chunk * 1024;
    float4 v = reinterpret_cast<const float4*>(src)[t];
    int f0 = v.x > 0.5f, f1 = v.y > 0.5f, f2 = v.z > 0.5f, f3 = v.w > 0.5f;
    int cnt = f0 + f1 + f2 + f3;
    __shared__ int s[256];
    s[t] = cnt; __syncthreads();
    for (int o = 1; o < 256; o <<= 1) {
        int x = (t >= o) ? s[t - o] : 0;
        __syncthreads();
        s[t] += x;
        __syncthreads();
    }
    int rank = offsets[cloud * NCHUNK + chunk] + (s[t] - cnt);
    int eidx = chunk * 1024 + t * 4;
    int flags[4] = {f0, f1, f2, f3};
    size_t base = (size_t)cloud * PTS_PAD;
    #pragma unroll
    for (int e = 0; e < 4; ++e) {
        if (flags[e]) {
            if (rank < MAXPTS) {
                int idx = eidx + e;
                int d = idx >> 12, h = (idx >> 6) & 63, w = idx & 63;
                int nr = d * d + h * h + w * w;
                half8 Q = {(_Float16)(-2 * d), (_Float16)(-2 * h), (_Float16)(-2 * w),
                           (_Float16)8, (_Float16)1, 0, 0, 0};
                half8 R = {(_Float16)d, (_Float16)h, (_Float16)w,
                           (_Float16)(nr >> 3), (_Float16)(nr & 7), 0, 0, 0};
                Qfrag[base + rank] = Q;
                Rfrag[base + rank] = R;
                nqint[base + rank] = (float)nr;
            }
            rank++;
        }
    }
}

// ---- min3-shaped reduce of one f32x16 + carry ------------------------------
__device__ __forceinline__ float red16(f32x16 d, float m) {
    float t0 = fminf(fminf(d[0], d[1]), d[2]);
    float t1 = fminf(fminf(d[3], d[4]), d[5]);
    float t2 = fminf(fminf(d[6], d[7]), d[8]);
    float t3 = fminf(fminf(d[9], d[10]), d[11]);
    float t4 = fminf(fminf(d[12], d[13]), d[14]);
    float t5 = fminf(d[15], m);
    float u0 = fminf(fminf(t0, t1), t2);
    float u1 = fminf(fminf(t3, t4), t5);
    return fminf(u0, u1);
}

// ---- Kernel 4: chamfer min via inline-asm 32x32x16 MFMA, refs from L2 ------
// grid = NTASK*NQB*RSPLIT = 1024 blocks (4/CU exactly), 256 thr (4 waves).
// Wave holds 160 queries (5 B-frags, lanes<32); streams 32 refs/step from L2.
// Per step: 1 global_load_dwordx4 + 5 MFMA (asm, "=v" dests) + 40 v_min3.
__global__ __launch_bounds__(256, 4) void k_chamfer(const half8* __restrict__ Qfrag,
                                                    const half8* __restrict__ Rfrag,
                                                    float* __restrict__ smin) {
    int task = blockIdx.x >> 7;          // /(NQB*RSPLIT)=128
    int rem  = blockIdx.x & 127;
    int qb   = rem >> 3;                 // /RSPLIT
    int rs   = rem & 7;
    int b = task >> 1, dir = task & 1;
    int qc = 2 * b + dir;
    int rc = 2 * b + (dir ^ 1);
    int tid = threadIdx.x, wave = tid >> 6, lane = tid & 63;
    int l32 = lane & 31;

    int qbase = qb * QPB + wave * QPW;
    half8 zero8 = {0, 0, 0, 0, 0, 0, 0, 0};
    half8 bq0 = zero8, bq1 = zero8, bq2 = zero8, bq3 = zero8, bq4 = zero8;
    if (lane < 32) {   // lanes>=32 supply k=8..15: zero nullifies A garbage there
        const half8* qp = Qfrag + (size_t)qc * PTS_PAD + qbase + l32;
        bq0 = qp[0]; bq1 = qp[32]; bq2 = qp[64]; bq3 = qp[96]; bq4 = qp[128];
    }
    float m0 = 1e30f, m1 = 1e30f, m2 = 1e30f, m3 = 1e30f, m4 = 1e30f;
    f32x16 cz;
    #pragma unroll
    for (int e = 0; e < 16; ++e) cz[e] = 0.f;

    const half8* rp = Rfrag + (size_t)rc * PTS_PAD + rs * RLEN + l32;
    half8 a = *rp;

#define STEP(aa)                                                               \
    do {                                                                       \
        f32x16 d0_, d1_, d2_;                                                  \
        asm("v_mfma_f32_32x32x16_f16 %0, %3, %4, %7\n\t"                       \
            "v_mfma_f32_32x32x16_f16 %1, %3, %5, %7\n\t"                       \
            "v_mfma_f32_32x32x16_f16 %2, %3, %6, %7\n\t"                       \
            "s_nop 7\n\ts_nop 7\n\ts_nop 7"                                    \
            : "=v"(d0_), "=v"(d1_), "=v"(d2_)                                  \
            : "v"(aa), "v"(bq0), "v"(bq1), "v"(bq2), "v"(cz));                 \
        m0 = red16(d0_, m0);                                                   \
        m1 = red16(d1_, m1);                                                   \
        m2 = red16(d2_, m2);                                                   \
        f32x16 e0_, e1_;                                                       \
        asm("v_mfma_f32_32x32x16_f16 %0, %2, %3, %5\n\t"                       \
            "v_mfma_f32_32x32x16_f16 %1, %2, %4, %5\n\t"                       \
            "s_nop 7\n\ts_nop 7\n\ts_nop 7"                                    \
            : "=v"(e0_), "=v"(e1_)                                             \
            : "v"(aa), "v"(bq3), "v"(bq4), "v"(cz));                           \
        m3 = red16(e0_, m3);                                                   \
        m4 = red16(e1_, m4);                                                   \
    } while (0)

    for (int t = 0; t < RSTEPS - 1; ++t) {
        rp += 32;
        half8 an = *rp;      // prefetch next 32 refs while MFMAs run
        STEP(a);
        a = an;
    }
    STEP(a);
#undef STEP

    // lane L and L+32 hold complementary ref-rows of query col (lane&31)
    m0 = fminf(m0, __shfl_xor(m0, 32));
    m1 = fminf(m1, __shfl_xor(m1, 32));
    m2 = fminf(m2, __shfl_xor(m2, 32));
    m3 = fminf(m3, __shfl_xor(m3, 32));
    m4 = fminf(m4, __shfl_xor(m4, 32));
    if (lane < 32) {
        float* outp = smin + ((size_t)task * RSPLIT + rs) * PTS_PAD + qbase + l32;
        outp[0]   = m0;
        outp[32]  = m1;
        outp[64]  = m2;
        outp[96]  = m3;
        outp[128] = m4;
    }
}

// ---- Kernel 5: min over splits, add nq, scale, clamp, masked block sum -----
__global__ void k_reduce(const float* __restrict__ nqint, const int* __restrict__ totals,
                         const float* __restrict__ smin, float* __restrict__ bsum) {
    int task = blockIdx.x / NRB;
    int rb   = blockIdx.x % NRB;
    int tid  = threadIdx.x;
    int qi   = rb * 256 + tid;
    int qc   = 2 * (task >> 1) + (task & 1);
    int countQ = min(totals[qc], MAXPTS);

    const float SC2 = SCALE * SCALE;
    float contrib = 0.f;
    if (qi < countQ) {
        const float* s = smin + (size_t)task * RSPLIT * PTS_PAD + qi;
        float mn = fminf(fminf(s[0 * PTS_PAD], s[1 * PTS_PAD]),
                         fminf(s[2 * PTS_PAD], s[3 * PTS_PAD]));
        mn = fminf(mn, fminf(fminf(s[4 * PTS_PAD], s[5 * PTS_PAD]),
                             fminf(s[6 * PTS_PAD], s[7 * PTS_PAD])));
        float nq = nqint[(size_t)qc * PTS_PAD + qi];
        contrib = fmaxf((nq + mn) * SC2, 0.f);
    }
    __shared__ float sb[256];
    sb[tid] = contrib; __syncthreads();
    for (int o = 128; o > 0; o >>= 1) {
        if (tid < o) sb[tid] += sb[tid + o];
        __syncthreads();
    }
    if (tid == 0) bsum[task * NRB + rb] = sb[0];
}

// ---- Kernel 6: deterministic final combine ---------------------------------
__global__ void k_final(const float* __restrict__ bsum, const int* __restrict__ totals,
                        float* __restrict__ out) {
    float total = 0.f, nv = 0.f;
    for (int b = 0; b < 4; ++b) {
        float s1 = 0.f, s2 = 0.f;
        for (int i = 0; i < NRB; ++i) {
            s1 += bsum[(2 * b) * NRB + i];
            s2 += bsum[(2 * b + 1) * NRB + i];
        }
        int c1 = min(totals[2 * b], MAXPTS);
        int c2 = min(totals[2 * b + 1], MAXPTS);
        float cd = s1 / fmaxf((float)c1, 1.f) + s2 / fmaxf((float)c2, 1.f);
        if (c1 > 0 && c2 > 0) { total += cd; nv += 1.f; }
    }
    out[0] = (nv > 0.f) ? total / nv : 0.f;
}

extern "C" void kernel_launch(void* const* d_in, const int* in_sizes, int n_in,
                              void* d_out, int out_size, void* d_ws, size_t ws_size,
                              hipStream_t stream) {
    const float* pred = (const float*)d_in[0];
    const float* tgt  = (const float*)d_in[1];
    float* out = (float*)d_out;

    char* ws = (char*)d_ws;
    int*   totals  = (int*)(ws + WS_TOTALS);
    int*   counts  = (int*)(ws + WS_COUNTS);
    int*   offsets = (int*)(ws + WS_OFFSETS);
    half8* Qfrag   = (half8*)(ws + WS_QFRAG);
    half8* Rfrag   = (half8*)(ws + WS_RFRAG);
    float* nqint   = (float*)(ws + WS_NQ);
    float* smin    = (float*)(ws + WS_SMIN);
    float* bsum    = (float*)(ws + WS_BSUM);

    k_count  <<<NCLOUD * NCHUNK, 256, 0, stream>>>(pred, tgt, counts, Qfrag, Rfrag, nqint);
    k_scan   <<<NCLOUD,          256, 0, stream>>>(counts, offsets, totals);
    k_compact<<<NCLOUD * NCHUNK, 256, 0, stream>>>(pred, tgt, offsets, Qfrag, Rfrag, nqint);
    k_chamfer<<<NTASK * NQB * RSPLIT, 256, 0, stream>>>(Qfrag, Rfrag, smin);
    k_reduce <<<NTASK * NRB,     256, 0, stream>>>(nqint, totals, smin, bsum);
    k_final  <<<1, 1, 0, stream>>>(bsum, totals, out);
}

// Round 9
// 54.053 us; speedup vs baseline: 1.1708x; 1.1209x over previous
//
#include <hip/hip_runtime.h>
#include <hip/hip_bf16.h>

// ChamferDistanceLoss via exact-integer f16 MFMA (32x32x16), inline-asm MFMA
// with "=&v" EARLY-CLOBBER dests (VGPR-class, disjoint from A/B operands --
// MFMA reads srcs across its 16 passes, so dest/src overlap corrupts).
// <=3 dests live (no spills); sched_barrier(0)-pinned issue/reduce interleave;
// every dest-read covered by >=24cyc s_nop + ~20cyc red16 of predecessor.
//   A (rows, L2-streamed)   = refs    enc [rd, rh, rw, nr>>3, nr&7, 0,0,0]
//   B (cols, register-held) = queries enc [-2qd, -2qh, -2qw, 8, 1, 0,0,0]
// B zeroed on lanes>=32 (k=8..15) -> A garbage there nullified.
// s = nr - 2 q.r exact; min commutes with +nq; scale by (2/63)^2 at the end.

#define NVOX      262144
#define NCHUNK    256
#define MAXPTS    10000
#define PTS_PAD   10240
#define NCLOUD    8
#define NTASK     8
#define NRB       40         // reduce blocks per task
#define QPW       160        // queries per wave (5 B-frags x 32)
#define QPB       640        // queries per block (4 waves)
#define NQB       16         // query blocks per task
#define RSPLIT    8          // ref splits per task
#define RLEN      1280       // refs per split
#define RSTEPS    40         // 32-ref steps per split
#define SCALE     (2.0f/63.0f)

typedef _Float16 half8  __attribute__((ext_vector_type(8)));
typedef float    f32x16 __attribute__((ext_vector_type(16)));

// ---------------- workspace layout (bytes) ----------------
#define WS_TOTALS   0           // 8 ints
#define WS_COUNTS   1024        // 8*256 ints
#define WS_OFFSETS  16384       // 8*256 ints
#define WS_QFRAG    32768       // 8*10240*16B = 1310720
#define WS_RFRAG    1343488     // 8*10240*16B = 1310720
#define WS_NQ       2654208     // 8*10240 f32 = 327680
#define WS_SMIN     2981888     // 8*8*10240 f32 = 2621440
#define WS_BSUM     5603328     // 8*40 f32

__device__ __forceinline__ const float* cloud_src(const float* pred, const float* tgt, int cloud) {
    const float* base = (cloud & 1) ? tgt : pred;
    return base + (size_t)(cloud >> 1) * NVOX;
}

// ---- Kernel 1: per-chunk active counts (+ pad init, merged) ----------------
__global__ void k_count(const float* __restrict__ pred, const float* __restrict__ tgt,
                        int* __restrict__ counts,
                        half8* __restrict__ Qfrag, half8* __restrict__ Rfrag,
                        float* __restrict__ nqint) {
    int gi = blockIdx.x * 256 + threadIdx.x;
    if (gi < NCLOUD * PTS_PAD) {   // init pads; compact overwrites ranks < total only
        half8 zq = {0, 0, 0, 0, 0, 0, 0, 0};
        half8 zr = {0, 0, 0, (_Float16)4096, 0, 0, 0, 0};   // pad ref: s=8*4096=32768 > any real
        Qfrag[gi] = zq;
        Rfrag[gi] = zr;
        nqint[gi] = 0.f;
    }
    int cloud = blockIdx.x >> 8;
    int chunk = blockIdx.x & 255;
    int t = threadIdx.x;
    const float* src = cloud_src(pred, tgt, cloud) + chunk * 1024;
    float4 v = reinterpret_cast<const float4*>(src)[t];
    int cnt = (v.x > 0.5f) + (v.y > 0.5f) + (v.z > 0.5f) + (v.w > 0.5f);
    __shared__ int s[256];
    s[t] = cnt; __syncthreads();
    for (int o = 128; o > 0; o >>= 1) {
        if (t < o) s[t] += s[t + o];
        __syncthreads();
    }
    if (t == 0) counts[cloud * NCHUNK + chunk] = s[0];
}

// ---- Kernel 2: exclusive scan of chunk counts per cloud --------------------
__global__ void k_scan(const int* __restrict__ counts, int* __restrict__ offsets,
                       int* __restrict__ totals) {
    int cloud = blockIdx.x;
    int t = threadIdx.x;
    int c = counts[cloud * NCHUNK + t];
    __shared__ int s[256];
    s[t] = c; __syncthreads();
    for (int o = 1; o < 256; o <<= 1) {
        int v = (t >= o) ? s[t - o] : 0;
        __syncthreads();
        s[t] += v;
        __syncthreads();
    }
    offsets[cloud * NCHUNK + t] = s[t] - c;
    if (t == 255) totals[cloud] = s[255];
}

// ---- Kernel 3: ordered compaction -> Q/R fragments + nq --------------------
__global__ void k_compact(const float* __restrict__ pred, const float* __restrict__ tgt,
                          const int* __restrict__ offsets,
                          half8* __restrict__ Qfrag, half8* __restrict__ Rfrag,
                          float* __restrict__ nqint) {
    int cloud = blockIdx.x >> 8;
    int chunk = blockIdx.x & 255;
    int t = threadIdx.x;
    const float* src = cloud_src(pred, tgt, cloud) + chunk * 1024;
    float4 v = reinterpret_cast<const float4*>(src)[t];
    int f0 = v.x > 0.5f, f1 = v.y > 0.5f, f2 = v.z > 0.5f, f3 = v.w > 0.5f;
    int cnt = f0 + f1 + f2 + f3;
    __shared__ int s[256];
    s[t] = cnt; __syncthreads();
    for (int o = 1; o < 256; o <<= 1) {
        int x = (t >= o) ? s[t - o] : 0;
        __syncthreads();
        s[t] += x;
        __syncthreads();
    }
    int rank = offsets[cloud * NCHUNK + chunk] + (s[t] - cnt);
    int eidx = chunk * 1024 + t * 4;
    int flags[4] = {f0, f1, f2, f3};
    size_t base = (size_t)cloud * PTS_PAD;
    #pragma unroll
    for (int e = 0; e < 4; ++e) {
        if (flags[e]) {
            if (rank < MAXPTS) {
                int idx = eidx + e;
                int d = idx >> 12, h = (idx >> 6) & 63, w = idx & 63;
                int nr = d * d + h * h + w * w;
                half8 Q = {(_Float16)(-2 * d), (_Float16)(-2 * h), (_Float16)(-2 * w),
                           (_Float16)8, (_Float16)1, 0, 0, 0};
                half8 R = {(_Float16)d, (_Float16)h, (_Float16)w,
                           (_Float16)(nr >> 3), (_Float16)(nr & 7), 0, 0, 0};
                Qfrag[base + rank] = Q;
                Rfrag[base + rank] = R;
                nqint[base + rank] = (float)nr;
            }
            rank++;
        }
    }
}

// ---- min3-shaped reduce of one f32x16 + carry (~9 VALU, >=20 cyc) ----------
__device__ __forceinline__ float red16(f32x16 d, float m) {
    float t0 = fminf(fminf(d[0], d[1]), d[2]);
    float t1 = fminf(fminf(d[3], d[4]), d[5]);
    float t2 = fminf(fminf(d[6], d[7]), d[8]);
    float t3 = fminf(fminf(d[9], d[10]), d[11]);
    float t4 = fminf(fminf(d[12], d[13]), d[14]);
    float t5 = fminf(d[15], m);
    float u0 = fminf(fminf(t0, t1), t2);
    float u1 = fminf(fminf(t3, t4), t5);
    return fminf(u0, u1);
}

#define SB __builtin_amdgcn_sched_barrier(0)

// single MFMA, C = inline 0, dest forced VGPR-class, EARLY-CLOBBER (disjoint
// from A/B: MFMA reads srcs across 16 passes while writing D)
#define MM(dd, aa, bb)                                                         \
    asm("v_mfma_f32_32x32x16_f16 %0, %1, %2, 0"                                \
        : "=&v"(dd) : "v"(aa), "v"(bb));                                       \
    SB
// variant with hazard padding after issue
#define MMP(dd, aa, bb)                                                        \
    asm("v_mfma_f32_32x32x16_f16 %0, %1, %2, 0\n\t"                            \
        "s_nop 7\n\ts_nop 7\n\ts_nop 7"                                        \
        : "=&v"(dd) : "v"(aa), "v"(bb));                                       \
    SB

// one 32-ref step: 5 MFMA + 5 red16, <=3 dests live; every dest-read is
// >=24cyc nops + ~20cyc red16 after its issue.
#define BODY(areg)                                                             \
    do {                                                                       \
        f32x16 d0_, d1_, d2_, d3_, d4_;                                        \
        MM(d0_, areg, bq0);                                                    \
        MMP(d1_, areg, bq1);                                                   \
        m0 = red16(d0_, m0); SB;                                               \
        MM(d2_, areg, bq2);                                                    \
        m1 = red16(d1_, m1); SB;                                               \
        MM(d3_, areg, bq3);                                                    \
        m2 = red16(d2_, m2); SB;                                               \
        MMP(d4_, areg, bq4);                                                   \
        m3 = red16(d3_, m3); SB;                                               \
        m4 = red16(d4_, m4); SB;                                               \
    } while (0)

// ---- Kernel 4: chamfer min via inline-asm 32x32x16 MFMA, refs from L2 ------
// grid = NTASK*NQB*RSPLIT = 1024 blocks (4/CU), 256 thr (4 waves), no LDS.
// Wave holds 160 queries (5 B-frags); streams 32 refs/step, depth-2 prefetch.
__global__ __launch_bounds__(256, 4) void k_chamfer(const half8* __restrict__ Qfrag,
                                                    const half8* __restrict__ Rfrag,
                                                    float* __restrict__ smin) {
    int task = blockIdx.x >> 7;          // /(NQB*RSPLIT)=128
    int rem  = blockIdx.x & 127;
    int qb   = rem >> 3;                 // /RSPLIT
    int rs   = rem & 7;
    int b = task >> 1, dir = task & 1;
    int qc = 2 * b + dir;
    int rc = 2 * b + (dir ^ 1);
    int tid = threadIdx.x, wave = tid >> 6, lane = tid & 63;
    int l32 = lane & 31;

    int qbase = qb * QPB + wave * QPW;
    half8 zero8 = {0, 0, 0, 0, 0, 0, 0, 0};
    half8 bq0 = zero8, bq1 = zero8, bq2 = zero8, bq3 = zero8, bq4 = zero8;
    if (lane < 32) {   // lanes>=32 supply k=8..15: zero nullifies A garbage there
        const half8* qp = Qfrag + (size_t)qc * PTS_PAD + qbase + l32;
        bq0 = qp[0]; bq1 = qp[32]; bq2 = qp[64]; bq3 = qp[96]; bq4 = qp[128];
    }
    float m0 = 1e30f, m1 = 1e30f, m2 = 1e30f, m3 = 1e30f, m4 = 1e30f;

    const half8* rp0 = Rfrag + (size_t)rc * PTS_PAD + rs * RLEN + l32;
    half8 a = rp0[0];
    half8 an = rp0[32];

    #pragma unroll 1
    for (int t = 0; t < RSTEPS - 2; ++t) {
        half8 a2 = rp0[32 * t + 64];   // depth-2 prefetch (~2 steps > L2 latency)
        BODY(a);
        a = an;
        an = a2;
    }
    BODY(a);
    BODY(an);

    // lane L and L+32 hold complementary ref-rows of query col (lane&31)
    m0 = fminf(m0, __shfl_xor(m0, 32));
    m1 = fminf(m1, __shfl_xor(m1, 32));
    m2 = fminf(m2, __shfl_xor(m2, 32));
    m3 = fminf(m3, __shfl_xor(m3, 32));
    m4 = fminf(m4, __shfl_xor(m4, 32));
    if (lane < 32) {
        float* outp = smin + ((size_t)task * RSPLIT + rs) * PTS_PAD + qbase + l32;
        outp[0]   = m0;
        outp[32]  = m1;
        outp[64]  = m2;
        outp[96]  = m3;
        outp[128] = m4;
    }
}

// ---- Kernel 5: min over splits, add nq, scale, clamp, masked block sum -----
__global__ void k_reduce(const float* __restrict__ nqint, const int* __restrict__ totals,
                         const float* __restrict__ smin, float* __restrict__ bsum) {
    int task = blockIdx.x / NRB;
    int rb   = blockIdx.x % NRB;
    int tid  = threadIdx.x;
    int qi   = rb * 256 + tid;
    int qc   = 2 * (task >> 1) + (task & 1);
    int countQ = min(totals[qc], MAXPTS);

    const float SC2 = SCALE * SCALE;
    float contrib = 0.f;
    if (qi < countQ) {
        const float* s = smin + (size_t)task * RSPLIT * PTS_PAD + qi;
        float mn = fminf(fminf(s[0 * PTS_PAD], s[1 * PTS_PAD]),
                         fminf(s[2 * PTS_PAD], s[3 * PTS_PAD]));
        mn = fminf(mn, fminf(fminf(s[4 * PTS_PAD], s[5 * PTS_PAD]),
                             fminf(s[6 * PTS_PAD], s[7 * PTS_PAD])));
        float nq = nqint[(size_t)qc * PTS_PAD + qi];
        contrib = fmaxf((nq + mn) * SC2, 0.f);
    }
    __shared__ float sb[256];
    sb[tid] = contrib; __syncthreads();
    for (int o = 128; o > 0; o >>= 1) {
        if (tid < o) sb[tid] += sb[tid + o];
        __syncthreads();
    }
    if (tid == 0) bsum[task * NRB + rb] = sb[0];
}

// ---- Kernel 6: deterministic final combine (8 parallel fixed-order sums) ---
__global__ void k_final(const float* __restrict__ bsum, const int* __restrict__ totals,
                        float* __restrict__ out) {
    int t = threadIdx.x;   // 64 threads
    __shared__ float sh[NTASK];
    if (t < NTASK) {
        float s = 0.f;
        #pragma unroll
        for (int i = 0; i < NRB; ++i) s += bsum[t * NRB + i];
        sh[t] = s;
    }
    __syncthreads();
    if (t == 0) {
        float total = 0.f, nv = 0.f;
        for (int b = 0; b < 4; ++b) {
            int c1 = min(totals[2 * b], MAXPTS);
            int c2 = min(totals[2 * b + 1], MAXPTS);
            float cd = sh[2 * b] / fmaxf((float)c1, 1.f) + sh[2 * b + 1] / fmaxf((float)c2, 1.f);
            if (c1 > 0 && c2 > 0) { total += cd; nv += 1.f; }
        }
        out[0] = (nv > 0.f) ? total / nv : 0.f;
    }
}

extern "C" void kernel_launch(void* const* d_in, const int* in_sizes, int n_in,
                              void* d_out, int out_size, void* d_ws, size_t ws_size,
                              hipStream_t stream) {
    const float* pred = (const float*)d_in[0];
    const float* tgt  = (const float*)d_in[1];
    float* out = (float*)d_out;

    char* ws = (char*)d_ws;
    int*   totals  = (int*)(ws + WS_TOTALS);
    int*   counts  = (int*)(ws + WS_COUNTS);
    int*   offsets = (int*)(ws + WS_OFFSETS);
    half8* Qfrag   = (half8*)(ws + WS_QFRAG);
    half8* Rfrag   = (half8*)(ws + WS_RFRAG);
    float* nqint   = (float*)(ws + WS_NQ);
    float* smin    = (float*)(ws + WS_SMIN);
    float* bsum    = (float*)(ws + WS_BSUM);

    k_count  <<<NCLOUD * NCHUNK, 256, 0, stream>>>(pred, tgt, counts, Qfrag, Rfrag, nqint);
    k_scan   <<<NCLOUD,          256, 0, stream>>>(counts, offsets, totals);
    k_compact<<<NCLOUD * NCHUNK, 256, 0, stream>>>(pred, tgt, offsets, Qfrag, Rfrag, nqint);
    k_chamfer<<<NTASK * NQB * RSPLIT, 256, 0, stream>>>(Qfrag, Rfrag, smin);
    k_reduce <<<NTASK * NRB,     256, 0, stream>>>(nqint, totals, smin, bsum);
    k_final  <<<1, 64, 0, stream>>>(bsum, totals, out);
}

// Round 10
// 50.670 us; speedup vs baseline: 1.2489x; 1.0668x over previous
//
#include <hip/hip_runtime.h>
#include <hip/hip_bf16.h>

// ChamferDistanceLoss via exact-integer f16 MFMA (32x32x16), builtin MFMA with
// LOW register pressure (2 dests live, ~80 VGPR) so regalloc keeps everything
// VGPR-class (no accvgpr copies) and min3 fuses. No inline asm, no
// sched_barrier -- compiler schedules loads/waits freely (m97 lesson).
//   A (rows, L2-streamed)   = refs    enc [rd, rh, rw, nr>>3, nr&7, 0,0,0]
//   B (cols, register-held) = queries enc [-2qd, -2qh, -2qw, 8, 1, 0,0,0]
// B zeroed on lanes>=32 (k=8..15) -> A garbage there nullified.
// s = nr - 2 q.r exact; min commutes with +nq; scale by (2/63)^2 at the end.

#define NVOX      262144
#define NCHUNK    256
#define MAXPTS    10000
#define PTS_PAD   10240
#define NCLOUD    8
#define NTASK     8
#define NRB       40         // reduce blocks per task
#define QPW       64         // queries per wave (2 B-frags x 32)
#define QPB       256        // queries per block (4 waves)
#define NQB       40         // query blocks per task
#define RSPLIT    4          // ref splits per task
#define RLEN      2560       // refs per split
#define RSTEPS    80         // 32-ref steps per split
#define SCALE     (2.0f/63.0f)

typedef _Float16 half8  __attribute__((ext_vector_type(8)));
typedef float    f32x16 __attribute__((ext_vector_type(16)));

// ---------------- workspace layout (bytes) ----------------
#define WS_TOTALS   0           // 8 ints
#define WS_COUNTS   1024        // 8*256 ints
#define WS_OFFSETS  16384       // 8*256 ints
#define WS_QFRAG    32768       // 8*10240*16B = 1310720
#define WS_RFRAG    1343488     // 8*10240*16B = 1310720
#define WS_NQ       2654208     // 8*10240 f32 = 327680
#define WS_SMIN     2981888     // 8*4*10240 f32 = 1310720
#define WS_BSUM     4292608     // 8*40 f32

__device__ __forceinline__ const float* cloud_src(const float* pred, const float* tgt, int cloud) {
    const float* base = (cloud & 1) ? tgt : pred;
    return base + (size_t)(cloud >> 1) * NVOX;
}

// ---- Kernel 1: per-chunk active counts (+ pad init, merged) ----------------
__global__ void k_count(const float* __restrict__ pred, const float* __restrict__ tgt,
                        int* __restrict__ counts,
                        half8* __restrict__ Qfrag, half8* __restrict__ Rfrag,
                        float* __restrict__ nqint) {
    int gi = blockIdx.x * 256 + threadIdx.x;
    if (gi < NCLOUD * PTS_PAD) {   // init pads; compact overwrites ranks < total only
        half8 zq = {0, 0, 0, 0, 0, 0, 0, 0};
        half8 zr = {0, 0, 0, (_Float16)4096, 0, 0, 0, 0};   // pad ref: s=8*4096=32768 > any real
        Qfrag[gi] = zq;
        Rfrag[gi] = zr;
        nqint[gi] = 0.f;
    }
    int cloud = blockIdx.x >> 8;
    int chunk = blockIdx.x & 255;
    int t = threadIdx.x;
    const float* src = cloud_src(pred, tgt, cloud) + chunk * 1024;
    float4 v = reinterpret_cast<const float4*>(src)[t];
    int cnt = (v.x > 0.5f) + (v.y > 0.5f) + (v.z > 0.5f) + (v.w > 0.5f);
    __shared__ int s[256];
    s[t] = cnt; __syncthreads();
    for (int o = 128; o > 0; o >>= 1) {
        if (t < o) s[t] += s[t + o];
        __syncthreads();
    }
    if (t == 0) counts[cloud * NCHUNK + chunk] = s[0];
}

// ---- Kernel 2: exclusive scan of chunk counts per cloud --------------------
__global__ void k_scan(const int* __restrict__ counts, int* __restrict__ offsets,
                       int* __restrict__ totals) {
    int cloud = blockIdx.x;
    int t = threadIdx.x;
    int c = counts[cloud * NCHUNK + t];
    __shared__ int s[256];
    s[t] = c; __syncthreads();
    for (int o = 1; o < 256; o <<= 1) {
        int v = (t >= o) ? s[t - o] : 0;
        __syncthreads();
        s[t] += v;
        __syncthreads();
    }
    offsets[cloud * NCHUNK + t] = s[t] - c;
    if (t == 255) totals[cloud] = s[255];
}

// ---- Kernel 3: ordered compaction -> Q/R fragments + nq --------------------
__global__ void k_compact(const float* __restrict__ pred, const float* __restrict__ tgt,
                          const int* __restrict__ offsets,
                          half8* __restrict__ Qfrag, half8* __restrict__ Rfrag,
                          float* __restrict__ nqint) {
    int cloud = blockIdx.x >> 8;
    int chunk = blockIdx.x & 255;
    int t = threadIdx.x;
    const float* src = cloud_src(pred, tgt, cloud) + chunk * 1024;
    float4 v = reinterpret_cast<const float4*>(src)[t];
    int f0 = v.x > 0.5f, f1 = v.y > 0.5f, f2 = v.z > 0.5f, f3 = v.w > 0.5f;
    int cnt = f0 + f1 + f2 + f3;
    __shared__ int s[256];
    s[t] = cnt; __syncthreads();
    for (int o = 1; o < 256; o <<= 1) {
        int x = (t >= o) ? s[t - o] : 0;
        __syncthreads();
        s[t] += x;
        __syncthreads();
    }
    int rank = offsets[cloud * NCHUNK + chunk] + (s[t] - cnt);
    int eidx = chunk * 1024 + t * 4;
    int flags[4] = {f0, f1, f2, f3};
    size_t base = (size_t)cloud * PTS_PAD;
    #pragma unroll
    for (int e = 0; e < 4; ++e) {
        if (flags[e]) {
            if (rank < MAXPTS) {
                int idx = eidx + e;
                int d = idx >> 12, h = (idx >> 6) & 63, w = idx & 63;
                int nr = d * d + h * h + w * w;
                half8 Q = {(_Float16)(-2 * d), (_Float16)(-2 * h), (_Float16)(-2 * w),
                           (_Float16)8, (_Float16)1, 0, 0, 0};
                half8 R = {(_Float16)d, (_Float16)h, (_Float16)w,
                           (_Float16)(nr >> 3), (_Float16)(nr & 7), 0, 0, 0};
                Qfrag[base + rank] = Q;
                Rfrag[base + rank] = R;
                nqint[base + rank] = (float)nr;
            }
            rank++;
        }
    }
}

// ---- min3-shaped reduce of one f32x16 + carry ------------------------------
__device__ __forceinline__ float red16(f32x16 d, float m) {
    float t0 = fminf(fminf(d[0], d[1]), d[2]);
    float t1 = fminf(fminf(d[3], d[4]), d[5]);
    float t2 = fminf(fminf(d[6], d[7]), d[8]);
    float t3 = fminf(fminf(d[9], d[10]), d[11]);
    float t4 = fminf(fminf(d[12], d[13]), d[14]);
    float t5 = fminf(d[15], m);
    float u0 = fminf(fminf(t0, t1), t2);
    float u1 = fminf(fminf(t3, t4), t5);
    return fminf(u0, u1);
}

// ---- Kernel 4: chamfer min via builtin 32x32x16 MFMA, refs from L2 ---------
// grid = NTASK*NQB*RSPLIT = 1280 blocks (5/CU), 256 thr (4 waves), no LDS.
// Wave holds 64 queries (2 B-frags); streams 32 refs/step, depth-2 prefetch.
// Per step: 1 global_load_dwordx4 + 2 MFMA + ~18 v_min3. ~80 VGPR live ->
// regalloc keeps MFMA dests VGPR-class; compiler schedules freely.
__global__ __launch_bounds__(256, 5) void k_chamfer(const half8* __restrict__ Qfrag,
                                                    const half8* __restrict__ Rfrag,
                                                    float* __restrict__ smin) {
    int task = blockIdx.x / (NQB * RSPLIT);
    int rem  = blockIdx.x % (NQB * RSPLIT);
    int qb   = rem / RSPLIT;
    int rs   = rem % RSPLIT;
    int b = task >> 1, dir = task & 1;
    int qc = 2 * b + dir;
    int rc = 2 * b + (dir ^ 1);
    int tid = threadIdx.x, wave = tid >> 6, lane = tid & 63;
    int l32 = lane & 31;

    int qbase = qb * QPB + wave * QPW;
    half8 zero8 = {0, 0, 0, 0, 0, 0, 0, 0};
    half8 bq0 = zero8, bq1 = zero8;
    if (lane < 32) {   // lanes>=32 supply k=8..15: zero nullifies A garbage there
        const half8* qp = Qfrag + (size_t)qc * PTS_PAD + qbase + l32;
        bq0 = qp[0]; bq1 = qp[32];
    }
    float m0 = 1e30f, m1 = 1e30f;
    f32x16 cz;
    #pragma unroll
    for (int e = 0; e < 16; ++e) cz[e] = 0.f;

    const half8* rp0 = Rfrag + (size_t)rc * PTS_PAD + rs * RLEN + l32;
    half8 a  = rp0[0];
    half8 an = rp0[32];

    for (int t = 0; t < RSTEPS - 2; ++t) {
        half8 a2 = rp0[32 * t + 64];   // depth-2 prefetch (~2 steps > L2 latency)
        f32x16 d0 = __builtin_amdgcn_mfma_f32_32x32x16_f16(a, bq0, cz, 0, 0, 0);
        f32x16 d1 = __builtin_amdgcn_mfma_f32_32x32x16_f16(a, bq1, cz, 0, 0, 0);
        m0 = red16(d0, m0);
        m1 = red16(d1, m1);
        a = an;
        an = a2;
    }
    {
        f32x16 d0 = __builtin_amdgcn_mfma_f32_32x32x16_f16(a, bq0, cz, 0, 0, 0);
        f32x16 d1 = __builtin_amdgcn_mfma_f32_32x32x16_f16(a, bq1, cz, 0, 0, 0);
        m0 = red16(d0, m0);
        m1 = red16(d1, m1);
        d0 = __builtin_amdgcn_mfma_f32_32x32x16_f16(an, bq0, cz, 0, 0, 0);
        d1 = __builtin_amdgcn_mfma_f32_32x32x16_f16(an, bq1, cz, 0, 0, 0);
        m0 = red16(d0, m0);
        m1 = red16(d1, m1);
    }

    // lane L and L+32 hold complementary ref-rows of query col (lane&31)
    m0 = fminf(m0, __shfl_xor(m0, 32));
    m1 = fminf(m1, __shfl_xor(m1, 32));
    if (lane < 32) {
        float* outp = smin + ((size_t)task * RSPLIT + rs) * PTS_PAD + qbase + l32;
        outp[0]  = m0;
        outp[32] = m1;
    }
}

// ---- Kernel 5: min over splits, add nq, scale, clamp, masked block sum -----
__global__ void k_reduce(const float* __restrict__ nqint, const int* __restrict__ totals,
                         const float* __restrict__ smin, float* __restrict__ bsum) {
    int task = blockIdx.x / NRB;
    int rb   = blockIdx.x % NRB;
    int tid  = threadIdx.x;
    int qi   = rb * 256 + tid;
    int qc   = 2 * (task >> 1) + (task & 1);
    int countQ = min(totals[qc], MAXPTS);

    const float SC2 = SCALE * SCALE;
    float contrib = 0.f;
    if (qi < countQ) {
        const float* s = smin + (size_t)task * RSPLIT * PTS_PAD + qi;
        float mn = fminf(fminf(s[0 * PTS_PAD], s[1 * PTS_PAD]),
                         fminf(s[2 * PTS_PAD], s[3 * PTS_PAD]));
        float nq = nqint[(size_t)qc * PTS_PAD + qi];
        contrib = fmaxf((nq + mn) * SC2, 0.f);
    }
    __shared__ float sb[256];
    sb[tid] = contrib; __syncthreads();
    for (int o = 128; o > 0; o >>= 1) {
        if (tid < o) sb[tid] += sb[tid + o];
        __syncthreads();
    }
    if (tid == 0) bsum[task * NRB + rb] = sb[0];
}

// ---- Kernel 6: deterministic final combine (8 parallel fixed-order sums) ---
__global__ void k_final(const float* __restrict__ bsum, const int* __restrict__ totals,
                        float* __restrict__ out) {
    int t = threadIdx.x;   // 64 threads
    __shared__ float sh[NTASK];
    if (t < NTASK) {
        float s = 0.f;
        #pragma unroll
        for (int i = 0; i < NRB; ++i) s += bsum[t * NRB + i];
        sh[t] = s;
    }
    __syncthreads();
    if (t == 0) {
        float total = 0.f, nv = 0.f;
        for (int b = 0; b < 4; ++b) {
            int c1 = min(totals[2 * b], MAXPTS);
            int c2 = min(totals[2 * b + 1], MAXPTS);
            float cd = sh[2 * b] / fmaxf((float)c1, 1.f) + sh[2 * b + 1] / fmaxf((float)c2, 1.f);
            if (c1 > 0 && c2 > 0) { total += cd; nv += 1.f; }
        }
        out[0] = (nv > 0.f) ? total / nv : 0.f;
    }
}

extern "C" void kernel_launch(void* const* d_in, const int* in_sizes, int n_in,
                              void* d_out, int out_size, void* d_ws, size_t ws_size,
                              hipStream_t stream) {
    const float* pred = (const float*)d_in[0];
    const float* tgt  = (const float*)d_in[1];
    float* out = (float*)d_out;

    char* ws = (char*)d_ws;
    int*   totals  = (int*)(ws + WS_TOTALS);
    int*   counts  = (int*)(ws + WS_COUNTS);
    int*   offsets = (int*)(ws + WS_OFFSETS);
    half8* Qfrag   = (half8*)(ws + WS_QFRAG);
    half8* Rfrag   = (half8*)(ws + WS_RFRAG);
    float* nqint   = (float*)(ws + WS_NQ);
    float* smin    = (float*)(ws + WS_SMIN);
    float* bsum    = (float*)(ws + WS_BSUM);

    k_count  <<<NCLOUD * NCHUNK, 256, 0, stream>>>(pred, tgt, counts, Qfrag, Rfrag, nqint);
    k_scan   <<<NCLOUD,          256, 0, stream>>>(counts, offsets, totals);
    k_compact<<<NCLOUD * NCHUNK, 256, 0, stream>>>(pred, tgt, offsets, Qfrag, Rfrag, nqint);
    k_chamfer<<<NTASK * NQB * RSPLIT, 256, 0, stream>>>(Qfrag, Rfrag, smin);
    k_reduce <<<NTASK * NRB,     256, 0, stream>>>(nqint, totals, smin, bsum);
    k_final  <<<1, 64, 0, stream>>>(bsum, totals, out);
}